// Round 5
// baseline (332.054 us; speedup 1.0000x reference)
//
#include <hip/hip_runtime.h>
#include <cstddef>
#include <cstdint>
#include <math.h>

typedef _Float16 f16;
typedef f16 f16x8 __attribute__((ext_vector_type(8)));
typedef f16 f16x4 __attribute__((ext_vector_type(4)));
typedef float f32x4 __attribute__((ext_vector_type(4)));

// ---------------- problem constants ----------------
constexpr int Bb   = 8;
constexpr int Ll   = 2048;
constexpr int Hin  = 128;
constexpr int Dm   = 512;
constexpr int Mrows = Bb * Ll;          // 16384
constexpr int NC   = 32;                // scan chunks per sequence
constexpr int CL   = Ll / NC;           // 64 timesteps per chunk
constexpr int SZ1  = Bb * NC * Dm;      // 131072 per state component

constexpr int TILE_ELE = 128 * 64;      // one 128x64 f16 tile = 16 KB

// ---------------- device math helpers ----------------
static __device__ __forceinline__ float sigmoid_f(float x) {
    return 1.f / (1.f + expf(-x));
}
static __device__ __forceinline__ float gelu_tanh_f(float x) {
    float x3 = x * x * x;
    float t  = tanhf(0.7978845608028654f * (x + 0.044715f * x3));
    return 0.5f * x * (1.f + t);
}

// async global->LDS, 16 bytes per lane (linear LDS dest: wave base + lane*16)
static __device__ __forceinline__ void gld16(const f16* g, f16* l) {
    __builtin_amdgcn_global_load_lds(
        (const __attribute__((address_space(1))) void*)g,
        (__attribute__((address_space(3))) void*)l, 16, 0, 0);
}

// ---------------- weight-product fusion precompute ----------------
// Wc1 = W_enc @ W_in  (512 x 128), bc1 = W_enc @ b_in + b_enc
__global__ __launch_bounds__(128) void fuse_wc1(
    const float* __restrict__ Wenc, const float* __restrict__ Win,
    const float* __restrict__ b_in, const float* __restrict__ b_enc,
    f16* __restrict__ Wc1, float* __restrict__ bc1)
{
    const int d2 = blockIdx.x;      // 0..511
    const int t  = threadIdx.x;     // 0..127
    float acc = 0.f;
    for (int d = 0; d < Dm; ++d)
        acc = fmaf(Wenc[d2 * Dm + d], Win[d * Hin + t], acc);
    Wc1[d2 * Hin + t] = (f16)acc;
    if (t == 0) {
        float s = 0.f;
        for (int d = 0; d < Dm; ++d) s = fmaf(Wenc[d2 * Dm + d], b_in[d], s);
        bc1[d2] = s + b_enc[d2];
    }
}

// Wc2 = W_out @ W_dec  (128 x 512), bc2 = W_out @ b_dec + b_out
__global__ __launch_bounds__(512) void fuse_wc2(
    const float* __restrict__ Wout, const float* __restrict__ Wdec,
    const float* __restrict__ b_dec, const float* __restrict__ b_out,
    f16* __restrict__ Wc2, float* __restrict__ bc2)
{
    const int o = blockIdx.x;   // 0..127
    const int t = threadIdx.x;  // 0..511
    float acc = 0.f;
    for (int d = 0; d < Dm; ++d)
        acc = fmaf(Wout[o * Dm + d], Wdec[d * Dm + t], acc);
    Wc2[o * Dm + t] = (f16)acc;
    if (t == 0) {
        float s = 0.f;
        for (int d = 0; d < Dm; ++d) s = fmaf(Wout[o * Dm + d], b_dec[d], s);
        bc2[o] = s + b_out[o];
    }
}

// ---------------- fp32 -> f16 conversion ----------------
struct CvtJob { const float* s; f16* d; int n; };
struct CvtJobs { CvtJob j[7]; };

__global__ __launch_bounds__(256) void convert_k(CvtJobs jobs) {
    const CvtJob jb = jobs.j[blockIdx.y];
    const int i = (blockIdx.x * 256 + threadIdx.x) * 4;
    if (i >= jb.n) return;
    const float4 v = *(const float4*)(jb.s + i);
    f16x4 o;
    o.x = (f16)v.x; o.y = (f16)v.y; o.z = (f16)v.z; o.w = (f16)v.w;
    *(f16x4*)(jb.d + i) = o;
}

// ---------------- fused MFMA GEMM (128x128 tile, BK=64, 2-phase dbuf) ----------
// All variants: 2 LDS tiles (A,B) double-buffered = 64 KB.
// KM=0: C = A@W^T + bias (bias may be null)
// KM=1: C = gelu( [A|A2] @ [W|W2]^T + DV[col]*EX )   -- concat-K=1024 (A2 pre-negated)
// KM=2: C = EX + EX2 * sigmoid(A@W^T + bias)          -- GLU combine (EX2 = g@w1^T+b1)
template <int KM, int OUTF16>
__global__ __launch_bounds__(256) void gemm_mfma(
    const f16* __restrict__ A, const f16* __restrict__ A2,
    const f16* __restrict__ W, const f16* __restrict__ W2,
    const float* __restrict__ bias,
    const f16* __restrict__ EX, const f16* __restrict__ EX2,
    const float* __restrict__ DV,
    void* __restrict__ Cout, int M, int N, int K)
{
    __shared__ f16 smem[4 * TILE_ELE];  // A0,A1,B0,B1

    const int tid = threadIdx.x;
    const int l   = tid & 63;
    const int wid = tid >> 6;
    const int wr  = wid >> 1;
    const int wc  = wid & 1;
    const int lc  = l & 15;
    const int lr  = l >> 4;
    const int row0 = blockIdx.x * 128;
    const int col0 = blockIdx.y * 128;

    const int Kst = (KM == 1) ? Dm : K;       // row stride of operands
    const int KL  = (KM == 1) ? 2 * Dm : K;   // logical K
    const int NT  = KL >> 6;

    const int swz  = (l & 7) << 4;
    const int off0 = ((lr * 16) ^ swz) >> 1;        // f16 elems
    const int off1 = ((64 + lr * 16) ^ swz) >> 1;

    f32x4 acc[4][4];
#pragma unroll
    for (int i = 0; i < 4; ++i)
#pragma unroll
        for (int j = 0; j < 4; ++j) acc[i][j] = (f32x4){0.f, 0.f, 0.f, 0.f};

    auto asrc = [&](int k0) -> const f16* {
        if (KM == 1 && k0 >= Dm) return A2 + (size_t)row0 * Dm + (k0 - Dm);
        return A + (size_t)row0 * Kst + k0;
    };
    auto wsrc = [&](int k0) -> const f16* {
        if (KM == 1 && k0 >= Dm) return W2 + (size_t)col0 * Dm + (k0 - Dm);
        return W + (size_t)col0 * Kst + k0;
    };

    // stage one 128x64 tile: linear LDS dest, inverse-swizzled global source
#define STAGE(DST, SRC)                                                      \
    {                                                                        \
        _Pragma("unroll")                                                    \
        for (int c = 0; c < 4; ++c) {                                        \
            const int chunk = c * 256 + tid;                                 \
            const int row   = chunk >> 3;                                    \
            const int kb    = ((chunk & 7) << 4) ^ ((row & 7) << 4);         \
            gld16(SRC + (size_t)row * Kst + (kb >> 1), DST + chunk * 8);     \
        }                                                                    \
    }

    STAGE(smem, asrc(0));
    STAGE(smem + 2 * TILE_ELE, wsrc(0));
    __syncthreads();

    int cur = 0;
    for (int kt = 0; kt < NT; ++kt) {
        if (kt + 1 < NT) {  // prefetch next K-tile while computing current
            STAGE(smem + (cur ^ 1) * TILE_ELE, asrc((kt + 1) << 6));
            STAGE(smem + (2 + (cur ^ 1)) * TILE_ELE, wsrc((kt + 1) << 6));
        }
        const f16* Asc = smem + cur * TILE_ELE;
        const f16* Bsc = smem + (2 + cur) * TILE_ELE;
#pragma unroll
        for (int ks = 0; ks < 2; ++ks) {
            const int off = ks ? off1 : off0;
            f16x8 aF[4], bF[4];
#pragma unroll
            for (int mi = 0; mi < 4; ++mi)
                aF[mi] = *(const f16x8*)(Asc + (wr * 64 + mi * 16 + lc) * 64 + off);
#pragma unroll
            for (int ni = 0; ni < 4; ++ni)
                bF[ni] = *(const f16x8*)(Bsc + (wc * 64 + ni * 16 + lc) * 64 + off);
#pragma unroll
            for (int mi = 0; mi < 4; ++mi)
#pragma unroll
                for (int ni = 0; ni < 4; ++ni)
                    acc[mi][ni] = __builtin_amdgcn_mfma_f32_16x16x32_f16(
                        aF[mi], bF[ni], acc[mi][ni], 0, 0, 0);
        }
        __syncthreads();
        cur ^= 1;
    }
#undef STAGE

    // ---------------- epilogue ----------------
    float* Cf32 = (float*)Cout;
    f16*   Cf16 = (f16*)Cout;
#pragma unroll
    for (int mi = 0; mi < 4; ++mi) {
#pragma unroll
        for (int ni = 0; ni < 4; ++ni) {
            const int col   = col0 + wc * 64 + ni * 16 + lc;
            const int rbase = row0 + wr * 64 + mi * 16 + lr * 4;
            const f32x4 v = acc[mi][ni];
            if (KM == 0) {
                const float bv = bias ? bias[col] : 0.f;
#pragma unroll
                for (int r = 0; r < 4; ++r) {
                    const float o = v[r] + bv;
                    const size_t idx = (size_t)(rbase + r) * N + col;
                    if (OUTF16) Cf16[idx] = (f16)o; else Cf32[idx] = o;
                }
            } else if (KM == 1) {
                const float dv = DV[col];
#pragma unroll
                for (int r = 0; r < 4; ++r) {
                    const size_t idx = (size_t)(rbase + r) * N + col;
                    const float o = gelu_tanh_f(v[r] + dv * (float)EX[idx]);
                    if (OUTF16) Cf16[idx] = (f16)o; else Cf32[idx] = o;
                }
            } else {
                const float bv = bias[col];
#pragma unroll
                for (int r = 0; r < 4; ++r) {
                    const size_t idx = (size_t)(rbase + r) * N + col;
                    const float o = (float)EX[idx] + (float)EX2[idx] * sigmoid_f(v[r] + bv);
                    if (OUTF16) Cf16[idx] = (f16)o; else Cf32[idx] = o;
                }
            }
        }
    }
}

// ---------------- LayerNorm (rows of 512, f16 in/out) ----------------
__global__ __launch_bounds__(256) void layernorm_f16(
    const f16* __restrict__ X, const float* __restrict__ g,
    const float* __restrict__ b, f16* __restrict__ Y)
{
    const int lane = threadIdx.x & 63;
    const int w    = threadIdx.x >> 6;
    const int row  = blockIdx.x * 4 + w;
    const size_t base = (size_t)row * Dm + lane * 8;

    const f16x8 v = *(const f16x8*)(X + base);
    float x[8];
    float s = 0.f, q = 0.f;
#pragma unroll
    for (int i = 0; i < 8; ++i) {
        x[i] = (float)v[i];
        s += x[i]; q += x[i] * x[i];
    }
#pragma unroll
    for (int off = 32; off > 0; off >>= 1) {
        s += __shfl_xor(s, off);
        q += __shfl_xor(q, off);
    }
    const float mu  = s * (1.f / 512.f);
    const float var = q * (1.f / 512.f) - mu * mu;
    const float rs  = rsqrtf(var + 1e-5f);

    const float4 g0 = *(const float4*)(g + lane * 8);
    const float4 g1 = *(const float4*)(g + lane * 8 + 4);
    const float4 b0 = *(const float4*)(b + lane * 8);
    const float4 b1 = *(const float4*)(b + lane * 8 + 4);
    const float gg[8] = {g0.x, g0.y, g0.z, g0.w, g1.x, g1.y, g1.z, g1.w};
    const float bb[8] = {b0.x, b0.y, b0.z, b0.w, b1.x, b1.y, b1.z, b1.w};
    f16x8 o;
#pragma unroll
    for (int i = 0; i < 8; ++i)
        o[i] = (f16)((x[i] - mu) * rs * gg[i] + bb[i]);
    *(f16x8*)(Y + base) = o;
}

// ---------------- scan constants ----------------
__global__ void consts_k(const float* __restrict__ A_diag,
                         const float* __restrict__ log_steps,
                         float* __restrict__ cst)
{
    const int n = threadIdx.x;
    const float a   = fmaxf(A_diag[n], 0.f);
    const float dt  = 1.f / (1.f + expf(-log_steps[n]));
    const float d2a = dt * dt * a;
    const float S   = 1.f / (1.f + d2a);
    const float m11 = 1.f - d2a * S;
    const float m12 = -dt * a * S;
    const float m21 = dt * S;
    const float m22 = S;
    cst[n]            = m11;
    cst[Dm + n]       = m12;
    cst[2 * Dm + n]   = m21;
    cst[3 * Dm + n]   = m22;
    cst[4 * Dm + n]   = m11 * dt;
    cst[5 * Dm + n]   = m21 * dt;
}

// ---------------- scan phase 1: per-chunk local final states (f16 Bu) --------
__global__ __launch_bounds__(512) void scan_phase1(
    const f16* __restrict__ bur, const f16* __restrict__ bui,
    const float* __restrict__ cst, float* __restrict__ S1)
{
    const int n = threadIdx.x;
    const int c = blockIdx.x & (NC - 1);
    const int b = blockIdx.x >> 5;
    const float m11 = cst[n],          m12 = cst[Dm + n];
    const float m21 = cst[2 * Dm + n], m22 = cst[3 * Dm + n];
    const float c1  = cst[4 * Dm + n], c2  = cst[5 * Dm + n];

    float zr = 0.f, xr = 0.f, zi = 0.f, xi = 0.f;
    const size_t base = ((size_t)b * Ll + (size_t)c * CL) * Dm + n;
#pragma unroll 4
    for (int t = 0; t < CL; ++t) {
        const float br = (float)bur[base + (size_t)t * Dm];
        const float bi = (float)bui[base + (size_t)t * Dm];
        const float zrn = fmaf(m11, zr, fmaf(m12, xr, c1 * br));
        const float xrn = fmaf(m21, zr, fmaf(m22, xr, c2 * br));
        const float zin = fmaf(m11, zi, fmaf(m12, xi, c1 * bi));
        const float xin = fmaf(m21, zi, fmaf(m22, xi, c2 * bi));
        zr = zrn; xr = xrn; zi = zin; xi = xin;
    }
    const int idx = blockIdx.x * Dm + n;
    S1[idx]            = zr;
    S1[SZ1 + idx]      = xr;
    S1[2 * SZ1 + idx]  = zi;
    S1[3 * SZ1 + idx]  = xi;
}

// ---------------- scan phase 2: inter-chunk exclusive scan ----------------
__global__ __launch_bounds__(256) void scan_phase2(
    const float* __restrict__ S1, const float* __restrict__ cst,
    float* __restrict__ G)
{
    const int gidx = blockIdx.x * 256 + threadIdx.x; // 0..4095
    const int n = gidx & (Dm - 1);
    const int b = gidx >> 9;
    const float m11 = cst[n],          m12 = cst[Dm + n];
    const float m21 = cst[2 * Dm + n], m22 = cst[3 * Dm + n];

    float p11 = 1.f, p12 = 0.f, p21 = 0.f, p22 = 1.f;
    for (int i = 0; i < CL; ++i) {
        const float q11 = m11 * p11 + m12 * p21;
        const float q12 = m11 * p12 + m12 * p22;
        const float q21 = m21 * p11 + m22 * p21;
        const float q22 = m21 * p12 + m22 * p22;
        p11 = q11; p12 = q12; p21 = q21; p22 = q22;
    }

    float gzr = 0.f, gxr = 0.f, gzi = 0.f, gxi = 0.f;
    for (int c = 0; c < NC; ++c) {
        const int idx = (b * NC + c) * Dm + n;
        G[idx]           = gzr;
        G[SZ1 + idx]     = gxr;
        G[2 * SZ1 + idx] = gzi;
        G[3 * SZ1 + idx] = gxi;
        const float szr = S1[idx],           sxr = S1[SZ1 + idx];
        const float szi = S1[2 * SZ1 + idx], sxi = S1[3 * SZ1 + idx];
        const float t1 = p11 * gzr + p12 * gxr + szr;
        const float t2 = p21 * gzr + p22 * gxr + sxr;
        const float t3 = p11 * gzi + p12 * gxi + szi;
        const float t4 = p21 * gzi + p22 * gxi + sxi;
        gzr = t1; gxr = t2; gzi = t3; gxi = t4;
    }
}

// ---------------- scan phase 3: re-scan; f16 xs out (imag negated) ----------
__global__ __launch_bounds__(512) void scan_phase3(
    const f16* __restrict__ bur, const f16* __restrict__ bui,
    const float* __restrict__ cst, const float* __restrict__ G,
    f16* __restrict__ xrf, f16* __restrict__ xif)
{
    const int n = threadIdx.x;
    const int c = blockIdx.x & (NC - 1);
    const int b = blockIdx.x >> 5;
    const float m11 = cst[n],          m12 = cst[Dm + n];
    const float m21 = cst[2 * Dm + n], m22 = cst[3 * Dm + n];
    const float c1  = cst[4 * Dm + n], c2  = cst[5 * Dm + n];

    const int sidx = blockIdx.x * Dm + n;
    float zr = G[sidx];
    float xr = G[SZ1 + sidx];
    float zi = G[2 * SZ1 + sidx];
    float xi = G[3 * SZ1 + sidx];

    const size_t base = ((size_t)b * Ll + (size_t)c * CL) * Dm + n;
#pragma unroll 4
    for (int t = 0; t < CL; ++t) {
        const float br = (float)bur[base + (size_t)t * Dm];
        const float bi = (float)bui[base + (size_t)t * Dm];
        const float zrn = fmaf(m11, zr, fmaf(m12, xr, c1 * br));
        const float xrn = fmaf(m21, zr, fmaf(m22, xr, c2 * br));
        const float zin = fmaf(m11, zi, fmaf(m12, xi, c1 * bi));
        const float xin = fmaf(m21, zi, fmaf(m22, xi, c2 * bi));
        zr = zrn; xr = xrn; zi = zin; xi = xin;
        xrf[base + (size_t)t * Dm] = (f16)xr;
        xif[base + (size_t)t * Dm] = (f16)(-xi);   // pre-negated for concat C-proj
    }
}

// ---------------- launch ----------------
extern "C" void kernel_launch(void* const* d_in, const int* in_sizes, int n_in,
                              void* d_out, int out_size, void* d_ws, size_t ws_size,
                              hipStream_t stream)
{
    const float* x         = (const float*)d_in[0];
    const float* W_in      = (const float*)d_in[1];
    const float* b_in      = (const float*)d_in[2];
    const float* W_enc     = (const float*)d_in[3];
    const float* b_enc     = (const float*)d_in[4];
    const float* ln_g      = (const float*)d_in[5];
    const float* ln_b      = (const float*)d_in[6];
    const float* A_diag    = (const float*)d_in[7];
    const float* log_steps = (const float*)d_in[8];
    const float* B_re      = (const float*)d_in[9];
    const float* B_im      = (const float*)d_in[10];
    const float* C_re      = (const float*)d_in[11];
    const float* C_im      = (const float*)d_in[12];
    const float* Dv        = (const float*)d_in[13];
    const float* glu_w1    = (const float*)d_in[14];
    const float* glu_b1    = (const float*)d_in[15];
    const float* glu_w2    = (const float*)d_in[16];
    const float* glu_b2    = (const float*)d_in[17];
    const float* W_dec     = (const float*)d_in[18];
    const float* b_dec     = (const float*)d_in[19];
    const float* W_out     = (const float*)d_in[20];
    const float* b_out     = (const float*)d_in[21];

    char* ws = (char*)d_ws;
    const size_t MB = 1 << 20;
    f16*   F2   = (f16*)(ws);             // skip f16, later h2 (KM2 out -> F3 actually)
    f16*   F3   = (f16*)(ws + 16 * MB);   // hn f16, later h2
    f16*   F0   = (f16*)(ws + 32 * MB);   // xs_re f16
    f16*   F1   = (f16*)(ws + 48 * MB);   // -xs_im f16
    f16*   BuRh = (f16*)(ws + 64 * MB);   // Bu_re f16; later P1 = g@w1^T+b1
    f16*   BuIh = (f16*)(ws + 80 * MB);   // Bu_im f16; later GF = g
    f16*   P1   = BuRh;
    f16*   GF   = BuIh;
    f16*   XF   = (f16*)(ws + 96 * MB);   // x f16 (4MB)
    float* S1   = (float*)(ws + 100 * MB);
    float* G    = (float*)(ws + 102 * MB);
    float* cst  = (float*)(ws + 104 * MB);
    f16*   Wc1  = (f16*)(ws + 105 * MB);  // 512x128
    f16*   Wc2  = (f16*)(ws + 106 * MB);  // 128x512
    float* bc1  = (float*)(ws + 107 * MB);
    float* bc2  = (float*)(ws + 107 * MB + 4096);
    f16*   wbuf = (f16*)(ws + 108 * MB);
    f16* BFRE = wbuf;                  // 262144 each
    f16* BFIM = BFRE + 262144;
    f16* CFRE = BFIM + 262144;
    f16* CFIM = CFRE + 262144;
    f16* W1F  = CFIM + 262144;
    f16* W2F  = W1F  + 262144;

    CvtJobs jobs;
    jobs.j[0] = {x,      XF,   Mrows * Hin};
    jobs.j[1] = {B_re,   BFRE, Dm * Dm};
    jobs.j[2] = {B_im,   BFIM, Dm * Dm};
    jobs.j[3] = {C_re,   CFRE, Dm * Dm};
    jobs.j[4] = {C_im,   CFIM, Dm * Dm};
    jobs.j[5] = {glu_w1, W1F,  Dm * Dm};
    jobs.j[6] = {glu_w2, W2F,  Dm * Dm};

    convert_k<<<dim3((Mrows * Hin) / 1024, 7), 256, 0, stream>>>(jobs);
    fuse_wc1<<<Dm, Hin, 0, stream>>>(W_enc, W_in, b_in, b_enc, Wc1, bc1);
    fuse_wc2<<<Hin, Dm, 0, stream>>>(W_out, W_dec, b_dec, b_out, Wc2, bc2);
    consts_k<<<1, Dm, 0, stream>>>(A_diag, log_steps, cst);

    dim3 blk(256);
    dim3 g512(Mrows / 128, Dm / 128);   // (128, 4)
    dim3 g128(Mrows / 128, Hin / 128);  // (128, 1)

    // skip = x @ Wc1^T + bc1   (fused in_proj+encoder, K=128)
    gemm_mfma<0, 1><<<g512, blk, 0, stream>>>(XF, nullptr, Wc1, nullptr, bc1,
                                              nullptr, nullptr, nullptr, F2, Mrows, Dm, Hin);
    // hn = layernorm(skip)
    layernorm_f16<<<Mrows / 4, 256, 0, stream>>>(F2, ln_g, ln_b, F3);
    // Bu_re/Bu_im = hn @ B^T (f16 out)
    gemm_mfma<0, 1><<<g512, blk, 0, stream>>>(F3, nullptr, BFRE, nullptr, nullptr,
                                              nullptr, nullptr, nullptr, BuRh, Mrows, Dm, Dm);
    gemm_mfma<0, 1><<<g512, blk, 0, stream>>>(F3, nullptr, BFIM, nullptr, nullptr,
                                              nullptr, nullptr, nullptr, BuIh, Mrows, Dm, Dm);
    // LinOSS scan (fp32 state)
    scan_phase1<<<Bb * NC, 512, 0, stream>>>(BuRh, BuIh, cst, S1);
    scan_phase2<<<(Bb * Dm) / 256, 256, 0, stream>>>(S1, cst, G);
    scan_phase3<<<Bb * NC, 512, 0, stream>>>(BuRh, BuIh, cst, G, F0, F1);
    // g = gelu([xs_re|-xs_im] @ [C_re|C_im]^T + D*hn)   (concat K=1024)
    gemm_mfma<1, 1><<<g512, blk, 0, stream>>>(F0, F1, CFRE, CFIM, nullptr,
                                              F3, nullptr, Dv, GF, Mrows, Dm, Dm);
    // P1 = g @ w1^T + b1
    gemm_mfma<0, 1><<<g512, blk, 0, stream>>>(GF, nullptr, W1F, nullptr, glu_b1,
                                              nullptr, nullptr, nullptr, P1, Mrows, Dm, Dm);
    // h2 = skip + P1 * sigmoid(g @ w2^T + b2)
    gemm_mfma<2, 1><<<g512, blk, 0, stream>>>(GF, nullptr, W2F, nullptr, glu_b2,
                                              F2, P1, nullptr, F3, Mrows, Dm, Dm);
    // out = h2 @ Wc2^T + bc2   (fused decoder+out_proj, N=128, fp32)
    gemm_mfma<0, 0><<<g128, blk, 0, stream>>>(F3, nullptr, Wc2, nullptr, bc2,
                                              nullptr, nullptr, nullptr, (float*)d_out, Mrows, Hin, Dm);
}